// Round 5
// baseline (252.855 us; speedup 1.0000x reference)
//
#include <hip/hip_runtime.h>
#include <stdint.h>

#define HID 1024
#define NEXP 8
#define NTOK 16384
#define CAP 8192

typedef __attribute__((ext_vector_type(8))) __bf16 bf16x8;
typedef __attribute__((ext_vector_type(8))) short short8;
typedef __attribute__((ext_vector_type(4))) float f32x4;

__device__ __forceinline__ ushort f2bf(float f) {
  uint32_t u = __builtin_bit_cast(uint32_t, f);
  u += 0x7FFF + ((u >> 16) & 1);          // round-to-nearest-even
  return (ushort)(u >> 16);
}
__device__ __forceinline__ float bf2f(ushort u) {
  return __builtin_bit_cast(float, (uint32_t)u << 16);
}

__device__ __forceinline__ void gl16(const void* g, void* l) {
  __builtin_amdgcn_global_load_lds((__attribute__((address_space(1))) void*)(g),
                                   (__attribute__((address_space(3))) void*)(l),
                                   16, 0, 0);
}

// ---------------- fp32 -> bf16 conversion (weights only) ----------------
__global__ void cvt_kernel(const float* __restrict__ src, ushort* __restrict__ dst, int n4) {
  int i = blockIdx.x * blockDim.x + threadIdx.x;
  int stride = gridDim.x * blockDim.x;
  for (; i < n4; i += stride) {
    float4 v = reinterpret_cast<const float4*>(src)[i];
    ushort4 o = make_ushort4(f2bf(v.x), f2bf(v.y), f2bf(v.z), f2bf(v.w));
    reinterpret_cast<ushort4*>(dst)[i] = o;
  }
}

__global__ void zero_kernel(int* counts) {
  if (threadIdx.x < NEXP) counts[threadIdx.x] = 0;
}

// ---------------- gate: fp32 logits + fused tokens->bf16 cvt; NO atomics ----------------
__global__ __launch_bounds__(256) void gate_kernel(
    const float* __restrict__ tokens, const float* __restrict__ gate_w,
    ushort* __restrict__ Xb,
    uint32_t* __restrict__ tinfo, float2* __restrict__ tw) {
  const int lane = threadIdx.x & 63;
  const int wave = threadIdx.x >> 6;
  float4 rg[NEXP][4];
#pragma unroll
  for (int e = 0; e < NEXP; e++)
#pragma unroll
    for (int j = 0; j < 4; j++)
      rg[e][j] = reinterpret_cast<const float4*>(gate_w)[e * 256 + j * 64 + lane];

  const int gwid = blockIdx.x * 4 + wave;
  const int nw = gridDim.x * 4;
  for (int t = gwid; t < NTOK; t += nw) {
    const float4* xr = reinterpret_cast<const float4*>(tokens + (size_t)t * HID);
    float acc[NEXP];
#pragma unroll
    for (int e = 0; e < NEXP; e++) acc[e] = 0.f;
    ushort4 xs[4];
#pragma unroll
    for (int j = 0; j < 4; j++) {
      float4 x = xr[j * 64 + lane];
      xs[j] = make_ushort4(f2bf(x.x), f2bf(x.y), f2bf(x.z), f2bf(x.w));
#pragma unroll
      for (int e = 0; e < NEXP; e++) {
        acc[e] = fmaf(x.x, rg[e][j].x,
                 fmaf(x.y, rg[e][j].y,
                 fmaf(x.z, rg[e][j].z,
                 fmaf(x.w, rg[e][j].w, acc[e]))));
      }
    }
    ushort4* xo = reinterpret_cast<ushort4*>(Xb + (size_t)t * HID);
#pragma unroll
    for (int j = 0; j < 4; j++) xo[j * 64 + lane] = xs[j];
#pragma unroll
    for (int e = 0; e < NEXP; e++) {
#pragma unroll
      for (int s = 32; s > 0; s >>= 1) acc[e] += __shfl_xor(acc[e], s);
    }
    int i1 = 0;
#pragma unroll
    for (int e = 1; e < NEXP; e++) if (acc[e] > acc[i1]) i1 = e;
    int i2 = (i1 == 0) ? 1 : 0;
#pragma unroll
    for (int e = 0; e < NEXP; e++) if (e != i1 && acc[e] > acc[i2]) i2 = e;
    float m = acc[i1];
    float s = 0.f;
#pragma unroll
    for (int e = 0; e < NEXP; e++) s += __expf(acc[e] - m);
    float w1 = 1.f / s;
    float w2 = __expf(acc[i2] - m) / s;
    if (lane == 0) {
      tinfo[t] = (uint32_t)i1 | ((uint32_t)i2 << 8);
      tw[t] = make_float2(w1, w2);
    }
  }
}

// ---------------- scatter: block-aggregated list build ----------------
__global__ __launch_bounds__(256) void scatter_kernel(
    const uint32_t* __restrict__ tinfo, const float2* __restrict__ tw,
    int* __restrict__ list, float* __restrict__ listw, int* __restrict__ counts) {
  __shared__ int lhist[NEXP];
  __shared__ int gbase[NEXP];
  const int tid = threadIdx.x;
  if (tid < NEXP) lhist[tid] = 0;
  __syncthreads();
  const int t = blockIdx.x * 256 + tid;
  uint32_t info = tinfo[t];
  int i1 = info & 0xFF, i2 = (info >> 8) & 0xFF;
  float2 w = tw[t];
  int lr1 = atomicAdd(&lhist[i1], 1);
  int lr2 = atomicAdd(&lhist[i2], 1);
  __syncthreads();
  if (tid < NEXP) gbase[tid] = atomicAdd(&counts[tid], lhist[tid]);
  __syncthreads();
  int p1 = gbase[i1] + lr1;
  if (p1 < CAP) { list[i1 * CAP + p1] = t;           listw[i1 * CAP + p1] = w.x; }
  int p2 = gbase[i2] + lr2;
  if (p2 < CAP) { list[i2 * CAP + p2] = t | 0x10000; listw[i2 * CAP + p2] = w.y; }
}

// ---------------- expert GEMM: 256x256x64 8-phase schedule (m201 template) ----------------
// LDS: As2/Bs2 [2 dbuf][256 rows][64 cols] bf16, 8-slot XOR swizzle (granule ^ row&7).
// Even K-tiles -> buf0, odd -> buf1 (static). vmcnt(4) at phases 4/8 only.
__global__ __launch_bounds__(512, 2) void egemm_kernel(
    const ushort* __restrict__ Ab, const ushort* __restrict__ Bb,
    const float* __restrict__ bias,
    const int* __restrict__ list, const float* __restrict__ listw,
    const int* __restrict__ counts, ushort* __restrict__ contrib) {
  __shared__ __align__(16) ushort As2[2 * 16384];
  __shared__ __align__(16) ushort Bs2[2 * 16384];
  const int tid = threadIdx.x, lane = tid & 63, wid = tid >> 6;
  // chunked XCD swizzle: XCD x gets logical blocks [x*128, x*128+128)
  const int d = blockIdx.x;
  const int l = (d & 7) * 128 + (d >> 3);
  const int e = l >> 7, rt = (l >> 2) & 31, ct = l & 3;
  int count = counts[e]; if (count > CAP) count = CAP;
  if (rt * 256 >= count) return;

  // ---- staging geometry (per 64-row sweep: 512 lanes x 16B) ----
  const int srow = wid * 8 + (lane >> 3);            // row within sweep
  const int sgr  = (lane & 7) ^ ((lane >> 3) & 7);   // pre-swizzled source granule
  int tok[2][2];
#pragma unroll
  for (int h = 0; h < 2; h++)
#pragma unroll
    for (int s = 0; s < 2; s++) {
      int r = rt * 256 + h * 128 + s * 64 + srow;
      tok[h][s] = (r < count) ? (list[e * CAP + r] & 0xFFFF) : 0;
    }
  const ushort* pA[2][2];
  const ushort* pB[2][2];
#pragma unroll
  for (int h = 0; h < 2; h++)
#pragma unroll
    for (int s = 0; s < 2; s++) {
      pA[h][s] = Ab + (size_t)tok[h][s] * HID + sgr * 8;
      pB[h][s] = Bb + (size_t)e * HID * HID +
                 (size_t)(ct * 256 + h * 128 + s * 64 + srow) * HID + sgr * 8;
    }
  ushort* AsP = As2;
  ushort* BsP = Bs2;

  // ---- fragment-read geometry ----
  const int fr = lane & 15, fq = lane >> 4;
  const int wm = wid >> 2, wn = wid & 3;
  const int c0 = (fq ^ (fr & 7)) * 8;          // kk=0 swizzled granule (ushorts)
  const int c1 = ((4 + fq) ^ (fr & 7)) * 8;    // kk=1
  const ushort* pa0 = As2 + wm * 8192 + fr * 64 + c0;
  const ushort* pa1 = As2 + wm * 8192 + fr * 64 + c1;
  const ushort* pb0 = Bs2 + wn * 4096 + fr * 64 + c0;
  const ushort* pb1 = Bs2 + wn * 4096 + fr * 64 + c1;

  f32x4 acc[8][4];
#pragma unroll
  for (int m = 0; m < 8; m++)
#pragma unroll
    for (int n = 0; n < 4; n++) acc[m][n] = (f32x4){0.f, 0.f, 0.f, 0.f};
  bf16x8 bfr[4][2];
  bf16x8 a00, a01, a10, a11;

#define STA(BUF, H, T) do { \
    gl16(pA[H][0] + (T) * 64, AsP + (BUF) * 16384 + (H) * 8192 + wid * 512); \
    gl16(pA[H][1] + (T) * 64, AsP + (BUF) * 16384 + (H) * 8192 + 4096 + wid * 512); } while (0)
#define STB(BUF, H, T) do { \
    gl16(pB[H][0] + (T) * 64, BsP + (BUF) * 16384 + (H) * 8192 + wid * 512); \
    gl16(pB[H][1] + (T) * 64, BsP + (BUF) * 16384 + (H) * 8192 + 4096 + wid * 512); } while (0)
#define BLD(B16K) do { \
    bfr[0][0] = *(const bf16x8*)(pb0 + (B16K));        bfr[0][1] = *(const bf16x8*)(pb1 + (B16K)); \
    bfr[1][0] = *(const bf16x8*)(pb0 + (B16K) + 1024); bfr[1][1] = *(const bf16x8*)(pb1 + (B16K) + 1024); \
    bfr[2][0] = *(const bf16x8*)(pb0 + (B16K) + 2048); bfr[2][1] = *(const bf16x8*)(pb1 + (B16K) + 2048); \
    bfr[3][0] = *(const bf16x8*)(pb0 + (B16K) + 3072); bfr[3][1] = *(const bf16x8*)(pb1 + (B16K) + 3072); } while (0)
#define ALD(B16K, M0) do { \
    a00 = *(const bf16x8*)(pa0 + (B16K) + (M0) * 1024); \
    a01 = *(const bf16x8*)(pa1 + (B16K) + (M0) * 1024); \
    a10 = *(const bf16x8*)(pa0 + (B16K) + ((M0) + 1) * 1024); \
    a11 = *(const bf16x8*)(pa1 + (B16K) + ((M0) + 1) * 1024); } while (0)
#define FMQ(M0) do { \
    acc[M0][0]   = __builtin_amdgcn_mfma_f32_16x16x32_bf16(a00, bfr[0][0], acc[M0][0], 0, 0, 0); \
    acc[M0][0]   = __builtin_amdgcn_mfma_f32_16x16x32_bf16(a01, bfr[0][1], acc[M0][0], 0, 0, 0); \
    acc[M0][1]   = __builtin_amdgcn_mfma_f32_16x16x32_bf16(a00, bfr[1][0], acc[M0][1], 0, 0, 0); \
    acc[M0][1]   = __builtin_amdgcn_mfma_f32_16x16x32_bf16(a01, bfr[1][1], acc[M0][1], 0, 0, 0); \
    acc[M0][2]   = __builtin_amdgcn_mfma_f32_16x16x32_bf16(a00, bfr[2][0], acc[M0][2], 0, 0, 0); \
    acc[M0][2]   = __builtin_amdgcn_mfma_f32_16x16x32_bf16(a01, bfr[2][1], acc[M0][2], 0, 0, 0); \
    acc[M0][3]   = __builtin_amdgcn_mfma_f32_16x16x32_bf16(a00, bfr[3][0], acc[M0][3], 0, 0, 0); \
    acc[M0][3]   = __builtin_amdgcn_mfma_f32_16x16x32_bf16(a01, bfr[3][1], acc[M0][3], 0, 0, 0); \
    acc[M0+1][0] = __builtin_amdgcn_mfma_f32_16x16x32_bf16(a10, bfr[0][0], acc[M0+1][0], 0, 0, 0); \
    acc[M0+1][0] = __builtin_amdgcn_mfma_f32_16x16x32_bf16(a11, bfr[0][1], acc[M0+1][0], 0, 0, 0); \
    acc[M0+1][1] = __builtin_amdgcn_mfma_f32_16x16x32_bf16(a10, bfr[1][0], acc[M0+1][1], 0, 0, 0); \
    acc[M0+1][1] = __builtin_amdgcn_mfma_f32_16x16x32_bf16(a11, bfr[1][1], acc[M0+1][1], 0, 0, 0); \
    acc[M0+1][2] = __builtin_amdgcn_mfma_f32_16x16x32_bf16(a10, bfr[2][0], acc[M0+1][2], 0, 0, 0); \
    acc[M0+1][2] = __builtin_amdgcn_mfma_f32_16x16x32_bf16(a11, bfr[2][1], acc[M0+1][2], 0, 0, 0); \
    acc[M0+1][3] = __builtin_amdgcn_mfma_f32_16x16x32_bf16(a10, bfr[3][0], acc[M0+1][3], 0, 0, 0); \
    acc[M0+1][3] = __builtin_amdgcn_mfma_f32_16x16x32_bf16(a11, bfr[3][1], acc[M0+1][3], 0, 0, 0); } while (0)
#define BAR __builtin_amdgcn_s_barrier()
#define LGKM0 do { asm volatile("s_waitcnt lgkmcnt(0)" ::: "memory"); __builtin_amdgcn_sched_barrier(0); } while (0)
#define VM4 asm volatile("s_waitcnt vmcnt(4)" ::: "memory")
#define SP1 __builtin_amdgcn_s_setprio(1)
#define SP0 __builtin_amdgcn_s_setprio(0)

  // prologue: tile0 (B then A, 8 loads) + tile1 B (4 loads)
  STB(0, 0, 0); STB(0, 1, 0); STA(0, 0, 0); STA(0, 1, 0);
  STB(1, 0, 1); STB(1, 1, 1);
  VM4; BAR;

#pragma unroll 1
  for (int i = 0; i < 8; ++i) {
    const int t1 = 2 * i + 1;
    const int tS2 = (2 * i + 2 < 16) ? 2 * i + 2 : 15;
    const int tS3 = (2 * i + 3 < 16) ? 2 * i + 3 : 15;
    // ph1: read B(t)+Aq0 from buf0; stage A(t+1)h0 -> buf1
    BLD(0); ALD(0, 0); STA(1, 0, t1);
    BAR; LGKM0; SP1; FMQ(0); SP0; BAR;
    // ph2
    ALD(0, 2); STA(1, 1, t1); STB(0, 0, tS2);
    BAR; LGKM0; SP1; FMQ(2); SP0; BAR;
    // ph3
    ALD(0, 4); STB(0, 1, tS2);
    BAR; LGKM0; SP1; FMQ(4); SP0; BAR;
    // ph4
    ALD(0, 6);
    BAR; LGKM0; SP1; FMQ(6); SP0; VM4; BAR;
    // ph5: read B(t+1)+Aq0 from buf1; stage A(t+2)h0 -> buf0
    BLD(16384); ALD(16384, 0); STA(0, 0, tS2);
    BAR; LGKM0; SP1; FMQ(0); SP0; BAR;
    // ph6
    ALD(16384, 2); STA(0, 1, tS2); STB(1, 0, tS3);
    BAR; LGKM0; SP1; FMQ(2); SP0; BAR;
    // ph7
    ALD(16384, 4); STB(1, 1, tS3);
    BAR; LGKM0; SP1; FMQ(4); SP0; BAR;
    // ph8
    ALD(16384, 6);
    BAR; LGKM0; SP1; FMQ(6); SP0; VM4; BAR;
  }
#undef STA
#undef STB
#undef BLD
#undef ALD
#undef FMQ

  // epilogue: silu(acc + b) * w -> contrib[slot][tok][col]
  const int colb = ct * 256 + wn * 64 + fr;
  float bc[4];
#pragma unroll
  for (int n = 0; n < 4; n++) bc[n] = bias[e * HID + colb + n * 16];
#pragma unroll
  for (int m = 0; m < 8; m++) {
#pragma unroll
    for (int rr = 0; rr < 4; rr++) {
      int r = rt * 256 + wm * 128 + m * 16 + fq * 4 + rr;
      if (r < count) {
        int ent = list[e * CAP + r];
        int tk = ent & 0xFFFF;
        int slot = (ent >> 16) & 1;
        float wgt = listw[e * CAP + r];
        ushort* dst = contrib + ((size_t)slot * NTOK + tk) * HID;
#pragma unroll
        for (int n = 0; n < 4; n++) {
          float v = acc[m][n][rr] + bc[n];
          float sv = v / (1.0f + __expf(-v));
          dst[colb + n * 16] = f2bf(sv * wgt);
        }
      }
    }
  }
}

// ---------------- combine GEMM with fused mix (A = c0+c1, reg-staged) ----------------
__global__ __launch_bounds__(256) void cgemm_kernel(
    const ushort* __restrict__ Cb, const ushort* __restrict__ Bb,
    float* __restrict__ outp) {
  __shared__ ushort As[2][128 * 32];
  __shared__ ushort Bs[2][128 * 32];
  const int tid = threadIdx.x, lane = tid & 63, wave = tid >> 6;
  const int p = blockIdx.x;
  const int cx = p & 7, q = p >> 3, ct = q & 7, rt = ((q >> 3) << 3) | cx;  // rt < 128

  const int cc0 = wave * 2;
  const int rl0 = cc0 * 16 + (lane >> 2);
  const int rl1 = rl0 + 16;
  const int nat8 = (lane & 3) * 8;
  const int swz8 = (((lane & 3) ^ ((lane >> 3) & 3))) * 8;

  const ushort* srcB0 = Bb + (size_t)(ct * 128 + rl0) * HID + swz8;
  const ushort* srcB1 = Bb + (size_t)(ct * 128 + rl1) * HID + swz8;
  const ushort* sA0c0 = Cb + (size_t)(rt * 128 + rl0) * HID + nat8;
  const ushort* sA0c1 = sA0c0 + (size_t)NTOK * HID;
  const ushort* sA1c0 = Cb + (size_t)(rt * 128 + rl1) * HID + nat8;
  const ushort* sA1c1 = sA1c0 + (size_t)NTOK * HID;
  const int wA0 = rl0 * 32 + swz8;
  const int wA1 = rl1 * 32 + swz8;

  f32x4 acc[4][4];
#pragma unroll
  for (int m = 0; m < 4; m++)
#pragma unroll
    for (int n = 0; n < 4; n++) acc[m][n] = (f32x4){0.f, 0.f, 0.f, 0.f};

  const int wm = wave >> 1, wn = wave & 1;
  const int fr = lane & 15, fq = lane >> 4;
  const int sa = (fq ^ ((fr >> 1) & 3)) * 8;

  auto bfadd8 = [](short8 a, short8 b) {
    short8 o;
#pragma unroll
    for (int j = 0; j < 8; j++)
      o[j] = (short)f2bf(bf2f((ushort)a[j]) + bf2f((ushort)b[j]));
    return o;
  };

  gl16(srcB0, &Bs[0][cc0 * 512]);
  gl16(srcB1, &Bs[0][cc0 * 512 + 512]);
  {
    short8 a0 = *reinterpret_cast<const short8*>(sA0c0);
    short8 b0 = *reinterpret_cast<const short8*>(sA0c1);
    short8 a1 = *reinterpret_cast<const short8*>(sA1c0);
    short8 b1 = *reinterpret_cast<const short8*>(sA1c1);
    *reinterpret_cast<short8*>(&As[0][wA0]) = bfadd8(a0, b0);
    *reinterpret_cast<short8*>(&As[0][wA1]) = bfadd8(a1, b1);
  }
  __syncthreads();
  gl16(srcB0 + 32, &Bs[1][cc0 * 512]);
  gl16(srcB1 + 32, &Bs[1][cc0 * 512 + 512]);
  short8 na0 = *reinterpret_cast<const short8*>(sA0c0 + 32);
  short8 nb0 = *reinterpret_cast<const short8*>(sA0c1 + 32);
  short8 na1 = *reinterpret_cast<const short8*>(sA1c0 + 32);
  short8 nb1 = *reinterpret_cast<const short8*>(sA1c1 + 32);

  for (int k0 = 0, t = 0; k0 < HID; k0 += 32, ++t) {
    const ushort* as = As[t & 1];
    const ushort* bs = Bs[t & 1];
    bf16x8 av[4], bv[4];
#pragma unroll
    for (int m = 0; m < 4; m++)
      av[m] = *reinterpret_cast<const bf16x8*>(&as[(wm * 64 + m * 16 + fr) * 32 + sa]);
#pragma unroll
    for (int n = 0; n < 4; n++)
      bv[n] = *reinterpret_cast<const bf16x8*>(&bs[(wn * 64 + n * 16 + fr) * 32 + sa]);
#pragma unroll
    for (int m = 0; m < 4; m++)
#pragma unroll
      for (int n = 0; n < 4; n++)
        acc[m][n] = __builtin_amdgcn_mfma_f32_16x16x32_bf16(av[m], bv[n], acc[m][n], 0, 0, 0);
    if (k0 + 32 < HID) {
      *reinterpret_cast<short8*>(&As[(t + 1) & 1][wA0]) = bfadd8(na0, nb0);
      *reinterpret_cast<short8*>(&As[(t + 1) & 1][wA1]) = bfadd8(na1, nb1);
    }
    __syncthreads();
    if (k0 + 64 < HID) {
      gl16(srcB0 + k0 + 64, &Bs[t & 1][cc0 * 512]);
      gl16(srcB1 + k0 + 64, &Bs[t & 1][cc0 * 512 + 512]);
      na0 = *reinterpret_cast<const short8*>(sA0c0 + k0 + 64);
      nb0 = *reinterpret_cast<const short8*>(sA0c1 + k0 + 64);
      na1 = *reinterpret_cast<const short8*>(sA1c0 + k0 + 64);
      nb1 = *reinterpret_cast<const short8*>(sA1c1 + k0 + 64);
    }
  }

  const int colb = ct * 128 + wn * 64 + fr;
#pragma unroll
  for (int m = 0; m < 4; m++)
#pragma unroll
    for (int rr = 0; rr < 4; rr++) {
      int r = rt * 128 + wm * 64 + m * 16 + fq * 4 + rr;
      float* dst = outp + (size_t)r * HID;
#pragma unroll
      for (int n = 0; n < 4; n++) dst[colb + n * 16] = acc[m][n][rr];
    }
}

extern "C" void kernel_launch(void* const* d_in, const int* in_sizes, int n_in,
                              void* d_out, int out_size, void* d_ws, size_t ws_size,
                              hipStream_t stream) {
  const float* tokens    = (const float*)d_in[0];
  const float* gate_w    = (const float*)d_in[1];
  const float* expert_w  = (const float*)d_in[2];
  const float* expert_b  = (const float*)d_in[3];
  const float* combine_w = (const float*)d_in[4];
  float* outp = (float*)d_out;

  char* p = (char*)d_ws;
  ushort* Xb  = (ushort*)p; p += (size_t)NTOK * HID * 2;        // 33.5 MB
  ushort* Wxb = (ushort*)p; p += (size_t)NEXP * HID * HID * 2;  // 16.8 MB
  ushort* Wcb = (ushort*)p; p += (size_t)HID * HID * 2;         //  2.1 MB
  ushort* ctb = (ushort*)p; p += (size_t)2 * NTOK * HID * 2;    // 67.1 MB
  int*   list = (int*)p;    p += (size_t)NEXP * CAP * 4;
  float* lsw  = (float*)p;  p += (size_t)NEXP * CAP * 4;
  int*   cnts = (int*)p;    p += 256;
  uint32_t* tinfo = (uint32_t*)p; p += (size_t)NTOK * 4;
  float2*   twp   = (float2*)p;   p += (size_t)NTOK * 8;

  zero_kernel<<<1, 64, 0, stream>>>(cnts);
  gate_kernel<<<2048, 256, 0, stream>>>(tokens, gate_w, Xb, tinfo, twp);
  cvt_kernel<<<1024, 256, 0, stream>>>(expert_w, Wxb, NEXP * HID * HID / 4);
  cvt_kernel<<<256, 256, 0, stream>>>(combine_w, Wcb, HID * HID / 4);
  scatter_kernel<<<64, 256, 0, stream>>>(tinfo, twp, list, lsw, cnts);
  egemm_kernel<<<1024, 512, 0, stream>>>(Xb, Wxb, expert_b, list, lsw, cnts, ctb);
  cgemm_kernel<<<1024, 256, 0, stream>>>(ctb, Wcb, outp);
}